// Round 17
// baseline (264.584 us; speedup 1.0000x reference)
//
#include <hip/hip_runtime.h>
#include <math.h>

namespace {

typedef short short8 __attribute__((ext_vector_type(8)));
typedef float f32x16 __attribute__((ext_vector_type(16)));
typedef unsigned int u32;
typedef unsigned long long u64;

constexpr int NEX = 256, LLEN = 2048, FEATS = 8192;
constexpr int PL = 512;          // 4*Dmax zeros on the left
constexpr int XSZ = 4096;

// packed bf16 split: (lo_bf16 << 16) | hi_bf16, both RNE
__device__ __forceinline__ u32 bfsplit(float x) {
  u32 b = __float_as_uint(x);
  u32 hb = (b + 0x7fffu + ((b >> 16) & 1u)) >> 16;
  float lo = x - __uint_as_float(hb << 16);
  u32 b2 = __float_as_uint(lo);
  u32 lb = (b2 + 0x7fffu + ((b2 >> 16) & 1u)) >> 16;
  return hb | (lb << 16);
}

__device__ __forceinline__ float max8(const float* v, int o) {
  float m0 = fmaxf(fmaxf(v[o+0], v[o+1]), v[o+2]);
  float m1 = fmaxf(fmaxf(v[o+3], v[o+4]), v[o+5]);
  float m2 = fmaxf(v[o+6], v[o+7]);
  return fmaxf(fmaxf(m0, m1), m2);
}
__device__ __forceinline__ float min8(const float* v, int o) {
  float m0 = fminf(fminf(v[o+0], v[o+1]), v[o+2]);
  float m1 = fminf(fminf(v[o+3], v[o+4]), v[o+5]);
  float m2 = fminf(v[o+6], v[o+7]);
  return fminf(fminf(m0, m1), m2);
}

#define MFMA __builtin_amdgcn_mfma_f32_32x32x16_bf16

template<int D, int DI>
__device__ __forceinline__ void body(
    const float* __restrict__ X, const float* __restrict__ W,
    float* __restrict__ out, u32* __restrict__ xhl,
    float* __restrict__ binsM, float* __restrict__ fin)
{
  const int n = blockIdx.x, diff = blockIdx.y, tid = threadIdx.x;
  const int lane = tid & 63, wave = tid >> 6;
  const int col = lane & 31, hi = lane >> 5;

  // ---- stage padded input as packed bf16 hi/lo (diff on the fly) ----
  const float* xr = X + n * LLEN;
  for (int i = tid; i < XSZ; i += 256) {
    float x = 0.f;
    if (diff) { if (i >= PL && i < PL + LLEN - 1) x = xr[i - PL + 1] - xr[i - PL]; }
    else      { if (i >= PL && i < PL + LLEN)     x = xr[i - PL]; }
    xhl[i] = bfsplit(x);
  }

  // ---- lane-private M bins, bank-invariant layout [wave][bin 0..31][lane]
  float* myM = binsM + wave * 2048 + lane;
  #pragma unroll
  for (int b = 0; b < 32; ++b) myM[b * 64] = 0.f;
  __syncthreads();

  const float* wall = W + (DI * 2 + diff) * (256 * 9);

  // Permuted A-row -> kernel map: lane owns two complete 8-k groups.
  const int g_of_r = ((col >> 4) << 1) | ((col >> 2) & 1);
  const int k_of_r = (col & 3) | (((col >> 3) & 1) << 2);
  const int kloc = g_of_r * 8 + k_of_r;

  // A fragments for BOTH 32-kern tiles (taps padded 9->16 with zeros)
  short8 ah0, al0, ah1, al1;
  {
    const float* w0 = wall + (wave * 64 + kloc) * 9;
    const float* w1 = w0 + 288;
    #pragma unroll
    for (int e = 0; e < 8; ++e) {
      int j = hi * 8 + e;
      float v0 = (j < 9) ? w0[j] : 0.f;
      float v1 = (j < 9) ? w1[j] : 0.f;
      u32 p0 = bfsplit(v0), p1 = bfsplit(v1);
      ah0[e] = (short)(p0 & 0xffffu); al0[e] = (short)(p0 >> 16);
      ah1[e] = (short)(p1 & 0xffffu); al1[e] = (short)(p1 >> 16);
    }
  }

  const f32x16 czero = {};
  u64 n00 = 0ull, n01 = 0ull, n10 = 0ull, n11 = 0ull;

  // epilogue for one MFMA result: embed index, trees, M-RMW, N-count
  #define EPI(c, BOFF, NA, NB)                                               \
    {                                                                        \
      float cf[16];                                                          \
      _Pragma("unroll")                                                      \
      for (int i = 0; i < 16; ++i)                                           \
        cf[i] = __uint_as_float((__float_as_uint(c[i]) & 0xFFFFFFF0u) |      \
                                (u32)(i & 7));                               \
      const float zx0 = max8(cf, 0), zn0 = min8(cf, 0);                      \
      const float zx1 = max8(cf, 8), zn1 = min8(cf, 8);                      \
      myM[((BOFF) + (__float_as_uint(zx0) & 7u)) * 64] += zx0;               \
      myM[((BOFF) + 8u + (__float_as_uint(zx1) & 7u)) * 64] += zx1;          \
      NA += 1ull << ((__float_as_uint(zn0) & 7u) * 8u);                      \
      NB += 1ull << ((__float_as_uint(zn1) & 7u) * 8u);                      \
    }

  // one t-position's two kern tiles, MFMAs wrapped in setprio(1)
  #define TILE2(BH, BL)                                                      \
    {                                                                        \
      f32x16 c0, c1;                                                         \
      __builtin_amdgcn_s_setprio(1);                                         \
      c0 = MFMA(al0, BH.s, czero, 0, 0, 0);                                  \
      c0 = MFMA(ah0, BL.s, c0,    0, 0, 0);                                  \
      c0 = MFMA(ah0, BH.s, c0,    0, 0, 0);                                  \
      c1 = MFMA(al1, BH.s, czero, 0, 0, 0);                                  \
      c1 = MFMA(ah1, BL.s, c1,    0, 0, 0);                                  \
      c1 = MFMA(ah1, BH.s, c1,    0, 0, 0);                                  \
      __builtin_amdgcn_s_setprio(0);                                         \
      EPI(c0, 0u, n00, n01)                                                  \
      EPI(c1, 16u, n10, n11)                                                 \
    }

  // 4x t-batch: issue all 32 ds_reads (16 x ds_read2_b32) up front, then
  // 8 MFMA-triple + epilogue blocks. Loop overhead quartered; deepest
  // load-ahead that fits the (256,3) ~170-reg budget.
  #pragma clang loop unroll_count(1)
  for (int tt4 = 0; tt4 < 16; ++tt4) {
    const int ebase = PL + tt4 * 128 + col + (hi * 8 - 4) * D;
    u32 uu[4][8];
    #pragma unroll
    for (int q = 0; q < 4; ++q) {
      #pragma unroll
      for (int p = 0; p < 4; ++p) {
        const u32* bp = xhl + (ebase + q * 32 + p * 2 * D);
        uu[q][2*p]   = bp[0];
        uu[q][2*p+1] = bp[D];
      }
    }
    union { short8 s; u32 u[4]; } bh[4], bl[4];
    #pragma unroll
    for (int q = 0; q < 4; ++q) {
      #pragma unroll
      for (int p = 0; p < 4; ++p) {
        bh[q].u[p] = __builtin_amdgcn_perm(uu[q][2*p+1], uu[q][2*p], 0x05040100u);
        bl[q].u[p] = __builtin_amdgcn_perm(uu[q][2*p+1], uu[q][2*p], 0x07060302u);
      }
    }
    TILE2(bh[0], bl[0])
    TILE2(bh[1], bl[1])
    TILE2(bh[2], bl[2])
    TILE2(bh[3], bl[3])
  }
  #undef TILE2
  #undef EPI

  // ---- single flush: lane = local kern s2 (0..63) of this wave ----
  const int kt2f = lane >> 5;
  const int s = lane & 31;
  const int hi_s = (s >> 3) & 1;
  const int chunk = s >> 4;
  const int kk = s & 7;
  float accM = 0.f;
  {
    const int b = kt2f * 16 + chunk * 8 + kk;
    const float* src = binsM + wave * 2048 + b * 64 + 32 * hi_s;
    #pragma unroll
    for (int c2 = 0; c2 < 32; ++c2) accM += src[(c2 + s) & 31];  // rotated
  }
  __syncthreads();   // fence: M reads complete before u32 staging overwrites

  // N staging into own (now dead) bins region: layout [word 0..7][lane]
  u32* nwp = (u32*)(binsM + wave * 2048);
  nwp[0 * 64 + lane] = (u32)n00; nwp[1 * 64 + lane] = (u32)(n00 >> 32);
  nwp[2 * 64 + lane] = (u32)n01; nwp[3 * 64 + lane] = (u32)(n01 >> 32);
  nwp[4 * 64 + lane] = (u32)n10; nwp[5 * 64 + lane] = (u32)(n10 >> 32);
  nwp[6 * 64 + lane] = (u32)n11; nwp[7 * 64 + lane] = (u32)(n11 >> 32);
  float accN;
  {
    const int w2 = kt2f * 4 + chunk * 2 + (kk >> 2);
    const u32 sh = (u32)(kk & 3) * 8u;
    const u32* srcn = nwp + w2 * 64 + 32 * hi_s;
    u32 a = 0;
    #pragma unroll
    for (int c2 = 0; c2 < 32; ++c2)
      a += (srcn[(c2 + s) & 31] >> sh) & 255u;                   // rotated
    accN = (float)a;
  }
  *(float2*)(fin + (wave * 64 + lane) * 2) = make_float2(accM, accN);
  __syncthreads();

  // ---- final: tid = kern (single owner) ----
  float2 mn2 = *(const float2*)(fin + tid * 2);
  float M = mn2.x, N = mn2.y;

  if (diff) {
    // remove the spurious t=2047 column (diff branch has 2047 timesteps)
    const float* wrow = wall + tid * 9;
    float z = 0.f;
    #pragma unroll
    for (int j = 0; j < 9; ++j) {
      u32 u = xhl[PL + (LLEN - 1) + (j - 4) * D];
      float xh = __uint_as_float((u & 0xffffu) << 16);
      float xl = __uint_as_float((u >> 16) << 16);
      u32 wp = bfsplit(wrow[j]);
      float wh = __uint_as_float((wp & 0xffffu) << 16);
      float wl = __uint_as_float((wp >> 16) << 16);
      z += wh * xh + wh * xl + wl * xh;
    }
    float* zrow = binsM;               // bins dead; barrier above fences reuse
    zrow[tid] = z;
    __syncthreads();
    const int h8 = tid & ~7;
    float zxv = zrow[h8], znv = zrow[h8];
    #pragma unroll
    for (int j = 1; j < 8; ++j) {
      zxv = fmaxf(zxv, zrow[h8 + j]);
      znv = fminf(znv, zrow[h8 + j]);
    }
    M -= (z == zxv) ? z : 0.f;
    N -= (z == znv) ? 1.f : 0.f;
  }

  const int base = n * FEATS + (DI * 4 + diff * 2) * 256 + tid;
  out[base]       = M > 0.f ? sqrtf(M) : 0.f;    // count_max
  out[base + 256] = N > 0.f ? sqrtf(N) : 0.f;    // count_min
}

__global__ __launch_bounds__(256, 3) void hydra_kernel(
    const float* __restrict__ X, const float* __restrict__ W,
    float* __restrict__ out)
{
  __shared__ u32   xhl[XSZ];               // 16 KB packed bf16 hi|lo
  __shared__ float binsM[4 * 32 * 64];     // 32 KB [wave][bin][lane], both kt2
  __shared__ float fin[512];               // 2 KB: [4][64]{M,N}
  // total 51200 B <= 54613 -> 3 blocks/CU
  switch (blockIdx.z) {
    case 0: body<1,   0>(X, W, out, xhl, binsM, fin); break;
    case 1: body<2,   1>(X, W, out, xhl, binsM, fin); break;
    case 2: body<4,   2>(X, W, out, xhl, binsM, fin); break;
    case 3: body<8,   3>(X, W, out, xhl, binsM, fin); break;
    case 4: body<16,  4>(X, W, out, xhl, binsM, fin); break;
    case 5: body<32,  5>(X, W, out, xhl, binsM, fin); break;
    case 6: body<64,  6>(X, W, out, xhl, binsM, fin); break;
    case 7: body<128, 7>(X, W, out, xhl, binsM, fin); break;
  }
}

} // namespace

extern "C" void kernel_launch(void* const* d_in, const int* in_sizes, int n_in,
                              void* d_out, int out_size, void* d_ws, size_t ws_size,
                              hipStream_t stream) {
  const float* X = (const float*)d_in[0];
  const float* W = (const float*)d_in[1];
  float* out = (float*)d_out;
  dim3 grid(NEX, 2, 8);
  hipLaunchKernelGGL(hydra_kernel, grid, dim3(256), 0, stream, X, W, out);
}